// Round 6
// baseline (245.383 us; speedup 1.0000x reference)
//
#include <hip/hip_runtime.h>
#include <math.h>

// NT-Xent (SimCLR) loss. B=4096, D=256, T=0.5.
// zb = bf16( SCALE * normalize(concat(emb_i, emb_j)) ), SCALE = sqrt(2*log2 e)
//   => acc = zb@zb^T = 2*log2(e)*sim, so exp(2*sim) == exp2(acc).
// Upper-triangle 128x128 tiles (exp matrix symmetric): tile (bx,by), bx<=by:
// rowsums -> denomP[by][rows bx], colsums -> denomP[bx][cols by]. Diagonal
// handled only in the 64 bx==by tiles. pos from the 32 by==bx+32 tiles.
// BK=128: 2 K-chunks, 4 barriers/block (was 8). LDS fragment-ordered: each
// MFMA fragment contiguous 1024B -> conflict-free lane-contiguous
// ds_read_b128; staging via global_load_lds width=16 (16x64B segments).
// Final reduction fused: last 32 blocks (by ticket) spin until all tiles
// done, then each reduces a 256-row slice into out[0] (2 launches total).
// loss = (1/8192) * ( (2*ln2)*sum_k posacc[k] - sum_r log(denom[r]) )

#define NROWS 8192
#define NHALF 4096
#define DIM   256
#define BM    128
#define BN    128
#define BK    128
#define NCB   (NROWS / BN)          // 64 row/col blocks
#define NTRI  (NCB * (NCB + 1) / 2) // 2080 triangle tiles
#define NRED  32                    // reducer blocks (last 32 tickets)

#define SCALE    1.69864344f   // sqrt(2*log2(e))
#define POSMUL   1.38629436f   // 4 / (2*log2(e)) = 2*ln2

typedef __attribute__((ext_vector_type(8))) short bf16x8;
typedef __attribute__((ext_vector_type(4))) float f32x4;

#if __has_builtin(__builtin_amdgcn_exp2f)
#define EXP2(x) __builtin_amdgcn_exp2f(x)
#else
#define EXP2(x) __expf((x) * 0.69314718f)
#endif

static __device__ __forceinline__ unsigned short f2bf(float x) {
  unsigned int u = __float_as_uint(x);
  unsigned int r = (u + 0x7FFFu + ((u >> 16) & 1u)) >> 16;
  return (unsigned short)r;
}

// --------------------- normalize (also zeroes out[0] and the ticket counter)
__global__ __launch_bounds__(256) void normalize_kernel(
    const float* __restrict__ emb_i, const float* __restrict__ emb_j,
    unsigned short* __restrict__ zb, float* __restrict__ out,
    int* __restrict__ cnt) {
  if (blockIdx.x == 0 && threadIdx.x == 0) { out[0] = 0.f; cnt[0] = 0; }
  int w = threadIdx.x >> 6, lane = threadIdx.x & 63;
  int row = blockIdx.x * 4 + w;
  const float* src = (row < NHALF) ? (emb_i + (size_t)row * DIM)
                                   : (emb_j + (size_t)(row - NHALF) * DIM);
  float4 v = ((const float4*)src)[lane];
  float ss = v.x * v.x + v.y * v.y + v.z * v.z + v.w * v.w;
  #pragma unroll
  for (int off = 32; off; off >>= 1) ss += __shfl_down(ss, off, 64);
  float total = __shfl(ss, 0, 64);
  float inv = SCALE / fmaxf(sqrtf(total), 1e-12f);
  ushort4 o;
  o.x = f2bf(v.x * inv); o.y = f2bf(v.y * inv);
  o.z = f2bf(v.z * inv); o.w = f2bf(v.w * inv);
  ((ushort4*)&zb[(size_t)row * DIM])[lane] = o;
}

// ---------------- MFMA GEMM + exp2 + sums + fused final reduction
__global__ __launch_bounds__(256) void denom_kernel(
    const unsigned short* __restrict__ zb, float* __restrict__ denomP,
    float* __restrict__ posv, int* __restrict__ cnt, float* __restrict__ out) {
  // 32 fragment regions x 1024 B per operand (32 KB each).
  __shared__ __attribute__((aligned(16))) unsigned short As[32 * 512];
  __shared__ __attribute__((aligned(16))) unsigned short Bs[32 * 512];

  // decode triangle tile id -> (bx, by), bx <= by
  int t = blockIdx.x;
  int by = (int)((sqrtf(8.0f * (float)t + 1.0f) - 1.0f) * 0.5f);
  while ((by + 1) * (by + 2) / 2 <= t) ++by;
  while (by * (by + 1) / 2 > t) --by;
  int bx = t - by * (by + 1) / 2;

  const int tid = threadIdx.x;
  const int w = tid >> 6;
  const int lane = tid & 63;
  const int wr = w >> 1, wc = w & 1;  // 2x2 wave grid, 64x64 each
  const int quad = lane >> 4;
  const int m16 = lane & 15;
  const int row0 = bx * BM;
  const int col0 = by * BN;

  f32x4 acc[4][4];
  #pragma unroll
  for (int i = 0; i < 4; ++i)
    #pragma unroll
    for (int j = 0; j < 4; ++j) {
      f32x4 z4 = {0.f, 0.f, 0.f, 0.f};
      acc[i][j] = z4;
    }

  // Region r (0..31): row-group g=r>>2 (rows g*16+m16), k-chunk c=r&3
  // (k = c*32 + quad*8). Wave w stages regions w*8..w*8+7 per operand.
  for (int kc = 0; kc < DIM; kc += BK) {
    #pragma unroll
    for (int t8 = 0; t8 < 8; ++t8) {
      int ra = w * 8 + t8;
      int grow = (ra >> 2) * 16 + m16;
      int gk = kc + (ra & 3) * 32 + quad * 8;
      __builtin_amdgcn_global_load_lds(
          (const __attribute__((address_space(1))) unsigned int*)
              &zb[(size_t)(row0 + grow) * DIM + gk],
          (__attribute__((address_space(3))) unsigned int*)&As[ra * 512],
          16, 0, 0);
      __builtin_amdgcn_global_load_lds(
          (const __attribute__((address_space(1))) unsigned int*)
              &zb[(size_t)(col0 + grow) * DIM + gk],
          (__attribute__((address_space(3))) unsigned int*)&Bs[ra * 512],
          16, 0, 0);
    }
    __syncthreads();

    #pragma unroll
    for (int kst = 0; kst < 4; ++kst) {
      bf16x8 af[4], bfr[4];
      #pragma unroll
      for (int i = 0; i < 4; ++i)
        af[i] = *(const bf16x8*)&As[(wr * 16 + i * 4 + kst) * 512 + lane * 8];
      #pragma unroll
      for (int j = 0; j < 4; ++j)
        bfr[j] = *(const bf16x8*)&Bs[(wc * 16 + j * 4 + kst) * 512 + lane * 8];
      #pragma unroll
      for (int i = 0; i < 4; ++i)
        #pragma unroll
        for (int j = 0; j < 4; ++j)
          acc[i][j] = __builtin_amdgcn_mfma_f32_16x16x32_bf16(
              af[i], bfr[j], acc[i][j], 0, 0, 0);
    }
    __syncthreads();
  }

  // pos extraction: only the 32 tiles with by == bx + 32 (block-uniform).
  if (col0 - row0 == NHALF) {
    #pragma unroll
    for (int i = 0; i < 4; ++i)
      #pragma unroll
      for (int j = 0; j < 4; ++j) {
        int gcol = col0 + wc * 64 + j * 16 + m16;
        #pragma unroll
        for (int r = 0; r < 4; ++r) {
          int grow = row0 + wr * 64 + i * 16 + quad * 4 + r;
          if (gcol - grow == NHALF) posv[grow] = acc[i][j][r];
        }
      }
  }

  // Epilogue. C layout: col = wc*64+j*16+m16, row = wr*64+i*16+quad*4+r.
  float* red = (float*)As;  // 512 floats after barrier

  if (bx != by) {
    // off-diagonal: predicate-free, row + column sums
    float rs[4][4];
    float cs[4] = {0.f, 0.f, 0.f, 0.f};
    #pragma unroll
    for (int i = 0; i < 4; ++i)
      #pragma unroll
      for (int r = 0; r < 4; ++r) rs[i][r] = 0.f;
    #pragma unroll
    for (int i = 0; i < 4; ++i)
      #pragma unroll
      for (int j = 0; j < 4; ++j)
        #pragma unroll
        for (int r = 0; r < 4; ++r) {
          float e = EXP2(acc[i][j][r]);
          rs[i][r] += e;
          cs[j] += e;
        }
    #pragma unroll
    for (int i = 0; i < 4; ++i)
      #pragma unroll
      for (int r = 0; r < 4; ++r) {
        float v = rs[i][r];
        v += __shfl_xor(v, 1, 16);
        v += __shfl_xor(v, 2, 16);
        v += __shfl_xor(v, 4, 16);
        v += __shfl_xor(v, 8, 16);
        if (m16 == 0) red[wc * 128 + wr * 64 + i * 16 + quad * 4 + r] = v;
      }
    #pragma unroll
    for (int j = 0; j < 4; ++j) {
      float v = cs[j];
      v += __shfl_xor(v, 16, 64);
      v += __shfl_xor(v, 32, 64);
      if (quad == 0) red[256 + wr * 128 + wc * 64 + j * 16 + m16] = v;
    }
    __syncthreads();
    if (tid < 128) {
      denomP[(size_t)by * NROWS + row0 + tid] = red[tid] + red[128 + tid];
    } else {
      int c = tid - 128;
      denomP[(size_t)bx * NROWS + col0 + c] = red[256 + c] + red[384 + c];
    }
  } else {
    // diagonal tile: rowsum only, local-diagonal skip
    float rs[4][4];
    #pragma unroll
    for (int i = 0; i < 4; ++i)
      #pragma unroll
      for (int r = 0; r < 4; ++r) rs[i][r] = 0.f;
    #pragma unroll
    for (int i = 0; i < 4; ++i)
      #pragma unroll
      for (int j = 0; j < 4; ++j) {
        int lcol = wc * 64 + j * 16 + m16;
        #pragma unroll
        for (int r = 0; r < 4; ++r) {
          int lrow = wr * 64 + i * 16 + quad * 4 + r;
          float e = (lrow == lcol) ? 0.f : EXP2(acc[i][j][r]);
          rs[i][r] += e;
        }
      }
    #pragma unroll
    for (int i = 0; i < 4; ++i)
      #pragma unroll
      for (int r = 0; r < 4; ++r) {
        float v = rs[i][r];
        v += __shfl_xor(v, 1, 16);
        v += __shfl_xor(v, 2, 16);
        v += __shfl_xor(v, 4, 16);
        v += __shfl_xor(v, 8, 16);
        if (m16 == 0) red[wc * 128 + wr * 64 + i * 16 + quad * 4 + r] = v;
      }
    __syncthreads();
    if (tid < 128)
      denomP[(size_t)bx * NROWS + row0 + tid] = red[tid] + red[128 + tid];
  }

  // ---- fused final reduction: last NRED tickets do 256-row slices ----
  __threadfence();  // make denomP/posv visible device-wide
  __shared__ int ticket_s;
  if (tid == 0) ticket_s = atomicAdd(cnt, 1);
  __syncthreads();
  int ticket = ticket_s;
  if (ticket < NTRI - NRED) return;
  int slice = ticket - (NTRI - NRED);

  if (tid == 0) {
    while (__hip_atomic_load(cnt, __ATOMIC_ACQUIRE,
                             __HIP_MEMORY_SCOPE_AGENT) < NTRI)
      __builtin_amdgcn_s_sleep(8);
  }
  __syncthreads();
  __threadfence();

  int r = slice * 256 + tid;
  float s = 0.f;
  #pragma unroll 8
  for (int b = 0; b < NCB; ++b) s += denomP[(size_t)b * NROWS + r];
  float v = -logf(s);
  if (r < NHALF) v += POSMUL * posv[r];
  #pragma unroll
  for (int off = 32; off; off >>= 1) v += __shfl_down(v, off, 64);
  if ((tid & 63) == 0) red[tid >> 6] = v;
  __syncthreads();
  if (tid == 0)
    atomicAdd(out, (red[0] + red[1] + red[2] + red[3]) * (1.0f / 8192.0f));
}

extern "C" void kernel_launch(void* const* d_in, const int* in_sizes, int n_in,
                              void* d_out, int out_size, void* d_ws,
                              size_t ws_size, hipStream_t stream) {
  const float* emb_i = (const float*)d_in[0];
  const float* emb_j = (const float*)d_in[1];
  unsigned short* zb = (unsigned short*)d_ws;            // 4 MB
  float* denomP = (float*)(zb + (size_t)NROWS * DIM);    // 64*8192 f32 (2 MB)
  float* posv = denomP + (size_t)NCB * NROWS;            // 4096 f32
  int* cnt = (int*)(posv + NHALF);                       // 1 int
  float* out = (float*)d_out;

  normalize_kernel<<<NROWS / 4, 256, 0, stream>>>(emb_i, emb_j, zb, out, cnt);
  denom_kernel<<<NTRI, 256, 0, stream>>>(zb, denomP, posv, cnt, out);
}

// Round 7
// 194.909 us; speedup vs baseline: 1.2590x; 1.2590x over previous
//
#include <hip/hip_runtime.h>
#include <math.h>

// NT-Xent (SimCLR) loss. B=4096, D=256, T=0.5.
// zb = bf16( SCALE * normalize(concat(emb_i, emb_j)) ), SCALE = sqrt(2*log2 e)
//   => acc = zb@zb^T = 2*log2(e)*sim, so exp(2*sim) == exp2(acc).
// SINGLE-WAVE blocks (64 thr), 64x64 tile, K=256, 16 KB LDS -> ~10 blocks/CU
// (R6 showed residency is the binding resource; 1-wave blocks also make
// __syncthreads barrier-free). Upper triangle of 64x64 tiles (8256 blocks):
// tile (bx,by) bx<=by adds its row sums (and col sums if bx<by) straight into
// dsum[8192] via device-scope fp32 atomicAdd (memory-side, cross-XCD safe,
// ~128 adds/address). Diagonal skipped in the 128 bx==by tiles. pos partial
// sums from the 64 by==bx+64 tiles -> atomicAdd(posSum).
// Fused finish, fence-free: after epilogue each block drains vmcnt(0) and
// takes a relaxed ticket; the last NRED tickets spin (acquire) until all
// 8256 blocks are done, then each -log()s a 64-row slice of dsum (agent
// atomic loads) into out[0]. 2 launches total.
// loss = (1/8192) * ( (2*ln2)*posSum - sum_r log(dsum[r]) )

#define NROWS 8192
#define NHALF 4096
#define DIM   256
#define NB    128                   // 64-row blocks
#define NTRI  (NB * (NB + 1) / 2)   // 8256 triangle tiles
#define NRED  128                   // reducer blocks (last 128 tickets)

#define SCALE    1.69864344f   // sqrt(2*log2(e))
#define POSMUL   1.38629436f   // 4 / (2*log2(e)) = 2*ln2

typedef __attribute__((ext_vector_type(8))) short bf16x8;
typedef __attribute__((ext_vector_type(4))) float f32x4;

#if __has_builtin(__builtin_amdgcn_exp2f)
#define EXP2(x) __builtin_amdgcn_exp2f(x)
#else
#define EXP2(x) __expf((x) * 0.69314718f)
#endif

static __device__ __forceinline__ unsigned short f2bf(float x) {
  unsigned int u = __float_as_uint(x);
  unsigned int r = (u + 0x7FFFu + ((u >> 16) & 1u)) >> 16;
  return (unsigned short)r;
}

// ---------------- normalize; also zeroes dsum / posSum / cnt / out ----------
__global__ __launch_bounds__(256) void normalize_kernel(
    const float* __restrict__ emb_i, const float* __restrict__ emb_j,
    unsigned short* __restrict__ zb, float* __restrict__ dsum,
    float* __restrict__ posSum, int* __restrict__ cnt,
    float* __restrict__ out) {
  if (blockIdx.x == 0 && threadIdx.x == 0) {
    out[0] = 0.f; posSum[0] = 0.f; cnt[0] = 0;
  }
  if (blockIdx.x < 32) dsum[blockIdx.x * 256 + threadIdx.x] = 0.f;
  int w = threadIdx.x >> 6, lane = threadIdx.x & 63;
  int row = blockIdx.x * 4 + w;
  const float* src = (row < NHALF) ? (emb_i + (size_t)row * DIM)
                                   : (emb_j + (size_t)(row - NHALF) * DIM);
  float4 v = ((const float4*)src)[lane];
  float ss = v.x * v.x + v.y * v.y + v.z * v.z + v.w * v.w;
  #pragma unroll
  for (int off = 32; off; off >>= 1) ss += __shfl_down(ss, off, 64);
  float total = __shfl(ss, 0, 64);
  float inv = SCALE / fmaxf(sqrtf(total), 1e-12f);
  ushort4 o;
  o.x = f2bf(v.x * inv); o.y = f2bf(v.y * inv);
  o.z = f2bf(v.z * inv); o.w = f2bf(v.w * inv);
  ((ushort4*)&zb[(size_t)row * DIM])[lane] = o;
}

// -------- single-wave MFMA tile + exp2 + atomic sums + fused final reduce ---
__global__ __launch_bounds__(64) void denom_kernel(
    const unsigned short* __restrict__ zb, float* __restrict__ dsum,
    float* __restrict__ posSum, int* __restrict__ cnt,
    float* __restrict__ out) {
  // 8 fragment regions x 1024 B per operand (8 KB each, 16 KB total).
  __shared__ __attribute__((aligned(16))) unsigned short As[8 * 512];
  __shared__ __attribute__((aligned(16))) unsigned short Bs[8 * 512];

  // decode triangle tile id -> (bx, by), bx <= by
  int t = blockIdx.x;
  int by = (int)((sqrtf(8.0f * (float)t + 1.0f) - 1.0f) * 0.5f);
  while ((by + 1) * (by + 2) / 2 <= t) ++by;
  while (by * (by + 1) / 2 > t) --by;
  int bx = t - by * (by + 1) / 2;

  const int lane = threadIdx.x;
  const int quad = lane >> 4;
  const int m16 = lane & 15;
  const int row0 = bx * 64;
  const int col0 = by * 64;

  f32x4 acc[4][4];
  #pragma unroll
  for (int i = 0; i < 4; ++i)
    #pragma unroll
    for (int j = 0; j < 4; ++j) {
      f32x4 z4 = {0.f, 0.f, 0.f, 0.f};
      acc[i][j] = z4;
    }

  // Region ra (0..7): row-group g=ra>>1 (rows g*16+m16), k-half c=ra&1
  // (k = c*32 + quad*8). Fragment-ordered: MFMA frag (i,kst) reads region
  // i*2+kst at byte offset lane*16 -> lane-contiguous ds_read_b128.
  for (int kc = 0; kc < DIM; kc += 64) {
    #pragma unroll
    for (int ra = 0; ra < 8; ++ra) {
      int grow = (ra >> 1) * 16 + m16;
      int gk = kc + (ra & 1) * 32 + quad * 8;
      __builtin_amdgcn_global_load_lds(
          (const __attribute__((address_space(1))) unsigned int*)
              &zb[(size_t)(row0 + grow) * DIM + gk],
          (__attribute__((address_space(3))) unsigned int*)&As[ra * 512],
          16, 0, 0);
      __builtin_amdgcn_global_load_lds(
          (const __attribute__((address_space(1))) unsigned int*)
              &zb[(size_t)(col0 + grow) * DIM + gk],
          (__attribute__((address_space(3))) unsigned int*)&Bs[ra * 512],
          16, 0, 0);
    }
    __builtin_amdgcn_s_waitcnt(0x0f70);  // vmcnt(0): LDS-DMA complete
    __syncthreads();                     // 1-wave: no cross-wave cost

    #pragma unroll
    for (int kst = 0; kst < 2; ++kst) {
      bf16x8 af[4], bfr[4];
      #pragma unroll
      for (int i = 0; i < 4; ++i)
        af[i] = *(const bf16x8*)&As[(i * 2 + kst) * 512 + lane * 8];
      #pragma unroll
      for (int j = 0; j < 4; ++j)
        bfr[j] = *(const bf16x8*)&Bs[(j * 2 + kst) * 512 + lane * 8];
      #pragma unroll
      for (int i = 0; i < 4; ++i)
        #pragma unroll
        for (int j = 0; j < 4; ++j)
          acc[i][j] = __builtin_amdgcn_mfma_f32_16x16x32_bf16(
              af[i], bfr[j], acc[i][j], 0, 0, 0);
    }
  }

  // pos extraction: tiles with col0 - row0 == NHALF (by == bx + 64).
  // Local match: j==i and m16 == quad*4 + r.
  if (col0 - row0 == NHALF) {
    float p = 0.f;
    int r = m16 - quad * 4;
    if (r >= 0 && r < 4) {
      #pragma unroll
      for (int i = 0; i < 4; ++i) p += acc[i][i][r];
    }
    #pragma unroll
    for (int off = 32; off; off >>= 1) p += __shfl_down(p, off, 64);
    if (lane == 0) atomicAdd(posSum, p);
  }

  // Epilogue. C layout: local col = j*16+m16, local row = i*16+quad*4+r.
  if (bx != by) {
    float rs[4][4];
    float cs[4] = {0.f, 0.f, 0.f, 0.f};
    #pragma unroll
    for (int i = 0; i < 4; ++i)
      #pragma unroll
      for (int r = 0; r < 4; ++r) rs[i][r] = 0.f;
    #pragma unroll
    for (int i = 0; i < 4; ++i)
      #pragma unroll
      for (int j = 0; j < 4; ++j)
        #pragma unroll
        for (int r = 0; r < 4; ++r) {
          float e = EXP2(acc[i][j][r]);
          rs[i][r] += e;
          cs[j] += e;
        }
    #pragma unroll
    for (int i = 0; i < 4; ++i)
      #pragma unroll
      for (int r = 0; r < 4; ++r) {
        float v = rs[i][r];
        v += __shfl_xor(v, 1, 16);
        v += __shfl_xor(v, 2, 16);
        v += __shfl_xor(v, 4, 16);
        v += __shfl_xor(v, 8, 16);
        if (m16 == 0) atomicAdd(&dsum[row0 + i * 16 + quad * 4 + r], v);
      }
    #pragma unroll
    for (int j = 0; j < 4; ++j) {
      float v = cs[j];
      v += __shfl_xor(v, 16, 64);
      v += __shfl_xor(v, 32, 64);
      if (quad == 0) atomicAdd(&dsum[col0 + j * 16 + m16], v);
    }
  } else {
    float rs[4][4];
    #pragma unroll
    for (int i = 0; i < 4; ++i)
      #pragma unroll
      for (int r = 0; r < 4; ++r) rs[i][r] = 0.f;
    #pragma unroll
    for (int i = 0; i < 4; ++i)
      #pragma unroll
      for (int j = 0; j < 4; ++j) {
        int lcol = j * 16 + m16;
        #pragma unroll
        for (int r = 0; r < 4; ++r) {
          int lrow = i * 16 + quad * 4 + r;
          float e = (lrow == lcol) ? 0.f : EXP2(acc[i][j][r]);
          rs[i][r] += e;
        }
      }
    #pragma unroll
    for (int i = 0; i < 4; ++i)
      #pragma unroll
      for (int r = 0; r < 4; ++r) {
        float v = rs[i][r];
        v += __shfl_xor(v, 1, 16);
        v += __shfl_xor(v, 2, 16);
        v += __shfl_xor(v, 4, 16);
        v += __shfl_xor(v, 8, 16);
        if (m16 == 0) atomicAdd(&dsum[row0 + i * 16 + quad * 4 + r], v);
      }
  }

  // ---- fence-free fused finish ----
  __builtin_amdgcn_s_waitcnt(0x0f70);  // drain this wave's atomics (vmcnt)
  int ticket = 0;
  if (lane == 0)
    ticket = __hip_atomic_fetch_add(cnt, 1, __ATOMIC_RELAXED,
                                    __HIP_MEMORY_SCOPE_AGENT);
  ticket = __shfl(ticket, 0, 64);
  if (ticket < NTRI - NRED) return;
  int slice = ticket - (NTRI - NRED);

  if (lane == 0) {
    while (__hip_atomic_load(cnt, __ATOMIC_ACQUIRE,
                             __HIP_MEMORY_SCOPE_AGENT) < NTRI)
      __builtin_amdgcn_s_sleep(8);
  }
  // wave reconverges after the masked spin

  int r = slice * 64 + lane;
  float s = __hip_atomic_load(&dsum[r], __ATOMIC_RELAXED,
                              __HIP_MEMORY_SCOPE_AGENT);
  float v = -logf(s);
  #pragma unroll
  for (int off = 32; off; off >>= 1) v += __shfl_down(v, off, 64);
  if (lane == 0) {
    if (slice == 0) {
      float ps = __hip_atomic_load(posSum, __ATOMIC_RELAXED,
                                   __HIP_MEMORY_SCOPE_AGENT);
      v += POSMUL * ps;
    }
    atomicAdd(out, v * (1.0f / 8192.0f));
  }
}

extern "C" void kernel_launch(void* const* d_in, const int* in_sizes, int n_in,
                              void* d_out, int out_size, void* d_ws,
                              size_t ws_size, hipStream_t stream) {
  const float* emb_i = (const float*)d_in[0];
  const float* emb_j = (const float*)d_in[1];
  unsigned short* zb = (unsigned short*)d_ws;         // 4 MB
  float* dsum = (float*)(zb + (size_t)NROWS * DIM);   // 8192 f32
  float* posSum = dsum + NROWS;                       // 1 f32
  int* cnt = (int*)(posSum + 1);                      // 1 int
  float* out = (float*)d_out;

  normalize_kernel<<<NROWS / 4, 256, 0, stream>>>(emb_i, emb_j, zb, dsum,
                                                  posSum, cnt, out);
  denom_kernel<<<NTRI, 64, 0, stream>>>(zb, dsum, posSum, cnt, out);
}